// Round 1
// baseline (358.685 us; speedup 1.0000x reference)
//
#include <hip/hip_runtime.h>

typedef unsigned short u16;
typedef __attribute__((ext_vector_type(8))) short short8;
typedef __attribute__((ext_vector_type(4))) float f32x4;

__device__ __forceinline__ u16 f2b(float f) {
  union { float f; unsigned u; } v; v.f = f;
  unsigned u = v.u;
  return (u16)((u + 0x7FFFu + ((u >> 16) & 1u)) >> 16);
}
__device__ __forceinline__ float b2f(u16 h) {
  union { unsigned u; float f; } v; v.u = ((unsigned)h) << 16; return v.f;
}

// ---------------- fp32 -> bf16 convert (4 elems/thread) ----------------
__global__ __launch_bounds__(256) void f32_to_bf16_k(const float* __restrict__ src,
                                                     u16* __restrict__ dst, int n) {
  int i4 = (blockIdx.x * 256 + threadIdx.x) * 4;
  if (i4 >= n) return;
  const float4 v = *(const float4*)(src + i4);
  uint2 o;
  o.x = (unsigned)f2b(v.x) | ((unsigned)f2b(v.y) << 16);
  o.y = (unsigned)f2b(v.z) | ((unsigned)f2b(v.w) << 16);
  *(uint2*)(dst + i4) = o;
}

// ---------------- sin/cos table: [S][32] ----------------
__global__ __launch_bounds__(256) void sincos_k(const int* __restrict__ pos,
                                                float* __restrict__ ct,
                                                float* __restrict__ st) {
  int idx = blockIdx.x * 256 + threadIdx.x;  // S*32
  int i = idx & 31, s = idx >> 5;
  float p = (float)pos[s];
  // inv_freq = 10000^(-i/32)
  float inv = expf(-(float)i * (logf(10000.0f) / 32.0f));
  float ang = p * inv;
  ct[idx] = cosf(ang);
  st[idx] = sinf(ang);
}

// ---------------- bf16 GEMM: C[M,N] = A[M,K] @ B[N,K]^T ----------------
// 128x128 tile, BK=32, 4 waves, each wave 64x64 (4x4 frags of 16x16).
// LDS layout: k8-plane-major, plane stride 1032 u16 (2064B, 16B pad per plane).
template <bool BF16OUT>
__global__ __launch_bounds__(256) void gemm_bt(const u16* __restrict__ A,
                                               const u16* __restrict__ B,
                                               void* __restrict__ Cv,
                                               int M, int N, int K) {
  __shared__ u16 As[4 * 1032];
  __shared__ u16 Bs[4 * 1032];
  const int tid = threadIdx.x;
  const int wv = tid >> 6, lane = tid & 63;
  const int quad = lane >> 4, l16 = lane & 15;
  const int wm = wv & 1, wn = wv >> 1;
  const int m0 = blockIdx.y * 128, n0 = blockIdx.x * 128;

  f32x4 acc[4][4];
  for (int i = 0; i < 4; i++)
    for (int j = 0; j < 4; j++) acc[i][j] = (f32x4){0.f, 0.f, 0.f, 0.f};

  for (int kt = 0; kt < K; kt += 32) {
    __syncthreads();
    {
      int c = tid;
      int row = c >> 2, k8 = c & 3;
      uint4 a = *(const uint4*)(A + (size_t)(m0 + row) * K + kt + k8 * 8);
      uint4 b = *(const uint4*)(B + (size_t)(n0 + row) * K + kt + k8 * 8);
      *(uint4*)(As + k8 * 1032 + row * 8) = a;
      *(uint4*)(Bs + k8 * 1032 + row * 8) = b;
      c = tid + 256;
      row = c >> 2; k8 = c & 3;
      uint4 a2 = *(const uint4*)(A + (size_t)(m0 + row) * K + kt + k8 * 8);
      uint4 b2 = *(const uint4*)(B + (size_t)(n0 + row) * K + kt + k8 * 8);
      *(uint4*)(As + k8 * 1032 + row * 8) = a2;
      *(uint4*)(Bs + k8 * 1032 + row * 8) = b2;
    }
    __syncthreads();
    short8 af[4], bfr[4];
    for (int i = 0; i < 4; i++)
      af[i] = *(const short8*)(As + quad * 1032 + (wm * 64 + i * 16 + l16) * 8);
    for (int j = 0; j < 4; j++)
      bfr[j] = *(const short8*)(Bs + quad * 1032 + (wn * 64 + j * 16 + l16) * 8);
    for (int i = 0; i < 4; i++)
      for (int j = 0; j < 4; j++)
        acc[i][j] = __builtin_amdgcn_mfma_f32_16x16x32_bf16(af[i], bfr[j], acc[i][j], 0, 0, 0);
  }
  // epilogue: C row = quad*4+reg, col = lane&15 (m89/m91-verified layout)
  for (int i = 0; i < 4; i++)
    for (int j = 0; j < 4; j++) {
      int col = n0 + wn * 64 + j * 16 + l16;
      for (int r = 0; r < 4; r++) {
        int row = m0 + wm * 64 + i * 16 + quad * 4 + r;
        if (BF16OUT)
          ((u16*)Cv)[(size_t)row * N + col] = f2b(acc[i][j][r]);
        else
          ((float*)Cv)[(size_t)row * N + col] = acc[i][j][r];
      }
    }
}

// ---------------- RoPE + repack: Cqkv bf16 [4096,3072] -> Qr/Kr/Vr [B,H,S,64] bf16 --------
__global__ __launch_bounds__(256) void repack_k(const u16* __restrict__ Cqkv,
                                                const float* __restrict__ ct,
                                                const float* __restrict__ st,
                                                u16* __restrict__ Qr,
                                                u16* __restrict__ Kr,
                                                u16* __restrict__ Vr) {
  int idx = blockIdx.x * 256 + threadIdx.x;  // B*S*H*32 = 2M
  int i = idx & 31;
  int h = (idx >> 5) & 15;
  int s = (idx >> 9) & 2047;
  int b = idx >> 20;
  size_t rowoff = (size_t)(b * 2048 + s) * 3072;
  int colq = h * 64 + 2 * i;
  unsigned qp = *(const unsigned*)(Cqkv + rowoff + colq);
  unsigned kp = *(const unsigned*)(Cqkv + rowoff + 1024 + colq);
  unsigned vp = *(const unsigned*)(Cqkv + rowoff + 2048 + colq);
  float qe = b2f((u16)qp), qo = b2f((u16)(qp >> 16));
  float ke = b2f((u16)kp), ko = b2f((u16)(kp >> 16));
  float c = ct[s * 32 + i], sn = st[s * 32 + i];
  float q0 = c * qe - sn * qo, q1 = sn * qe + c * qo;
  float k0 = c * ke - sn * ko, k1 = sn * ke + c * ko;
  size_t o = ((size_t)(b * 16 + h) * 2048 + s) * 64 + 2 * i;
  *(unsigned*)(Qr + o) = (unsigned)f2b(q0) | ((unsigned)f2b(q1) << 16);
  *(unsigned*)(Kr + o) = (unsigned)f2b(k0) | ((unsigned)f2b(k1) << 16);
  *(unsigned*)(Vr + o) = vp;
}

// ---------------- flash attention: 1 block per (b,h, 64-row q tile) ----------------
// Tiles: BQ=BK=64, dk=64. LDS plane layout: plane stride 520 u16 (1040B).
__global__ __launch_bounds__(256) void attn_k(const u16* __restrict__ Q,
                                              const u16* __restrict__ K,
                                              const u16* __restrict__ V,
                                              u16* __restrict__ O, int S) {
  __shared__ u16 Qs[8 * 520], Ks[8 * 520], Vt[8 * 520], Ps[8 * 520];
  __shared__ float Sc[64 * 65];
  __shared__ float rowm[64], rowl[64], alpha_s[64], pmax[4 * 64], psum[4 * 64];

  const int tid = threadIdx.x;
  const int wv = tid >> 6, lane = tid & 63, quad = lane >> 4, l16 = lane & 15;
  const int qt = blockIdx.x, bh = blockIdx.y;
  const int q0 = qt * 64;
  const u16* Qg = Q + (size_t)bh * S * 64;
  const u16* Kg = K + (size_t)bh * S * 64;
  const u16* Vg = V + (size_t)bh * S * 64;

  for (int c = tid; c < 512; c += 256) {
    int row = c >> 3, k8 = c & 7;
    uint4 v = *(const uint4*)(Qg + (size_t)(q0 + row) * 64 + k8 * 8);
    *(uint4*)(Qs + k8 * 520 + row * 8) = v;
  }
  if (tid < 64) { rowm[tid] = -1e30f; rowl[tid] = 0.f; }
  __syncthreads();

  short8 qa[2];
  {
    int r = wv * 16 + l16;
    qa[0] = *(const short8*)(Qs + (0 + quad) * 520 + r * 8);
    qa[1] = *(const short8*)(Qs + (4 + quad) * 520 + r * 8);
  }

  f32x4 oacc[4];
  for (int j = 0; j < 4; j++) oacc[j] = (f32x4){0.f, 0.f, 0.f, 0.f};
  const float scale = 0.125f;  // 1/sqrt(64)
  const int mrow = wv * 16 + quad * 4;

  for (int kt = 0; kt <= qt; ++kt) {
    const int k0 = kt * 64;
    __syncthreads();  // previous iteration's LDS consumers done
    for (int c = tid; c < 512; c += 256) {
      int row = c >> 3, k8 = c & 7;
      uint4 v = *(const uint4*)(Kg + (size_t)(k0 + row) * 64 + k8 * 8);
      *(uint4*)(Ks + k8 * 520 + row * 8) = v;
    }
    for (int c = tid; c < 512; c += 256) {
      int sl = c >> 3, d8 = c & 7;
      u16 tmp[8];
      *(uint4*)tmp = *(const uint4*)(Vg + (size_t)(k0 + sl) * 64 + d8 * 8);
      int kp = sl >> 3, ko = sl & 7;
      for (int i = 0; i < 8; i++) Vt[kp * 520 + (d8 * 8 + i) * 8 + ko] = tmp[i];
    }
    __syncthreads();
    // S = Q K^T (scaled, causally masked) -> Sc
    for (int nt = 0; nt < 4; ++nt) {
      f32x4 sc = (f32x4){0.f, 0.f, 0.f, 0.f};
      short8 b0 = *(const short8*)(Ks + (0 + quad) * 520 + (nt * 16 + l16) * 8);
      short8 b1 = *(const short8*)(Ks + (4 + quad) * 520 + (nt * 16 + l16) * 8);
      sc = __builtin_amdgcn_mfma_f32_16x16x32_bf16(qa[0], b0, sc, 0, 0, 0);
      sc = __builtin_amdgcn_mfma_f32_16x16x32_bf16(qa[1], b1, sc, 0, 0, 0);
      int col = nt * 16 + l16;
      for (int r = 0; r < 4; r++) {
        float val = sc[r] * scale;
        if (kt == qt && col > mrow + r) val = -1e30f;
        Sc[(mrow + r) * 65 + col] = val;
      }
    }
    __syncthreads();
    {  // partial row max
      int row = tid & 63, seg = tid >> 6;
      const float* p = Sc + row * 65 + seg * 16;
      float m = p[0];
      for (int j = 1; j < 16; j++) m = fmaxf(m, p[j]);
      pmax[seg * 64 + row] = m;
    }
    __syncthreads();
    if (tid < 64) {
      float mnew = fmaxf(fmaxf(pmax[tid], pmax[64 + tid]), fmaxf(pmax[128 + tid], pmax[192 + tid]));
      mnew = fmaxf(mnew, rowm[tid]);
      alpha_s[tid] = __expf(rowm[tid] - mnew);
      rowm[tid] = mnew;
    }
    __syncthreads();
    {  // exp, write P (bf16, A-layout planes), partial sums
      int row = tid & 63, seg = tid >> 6;
      float mr = rowm[row];
      float sum = 0.f;
      const float* p = Sc + row * 65 + seg * 16;
      for (int j = 0; j < 16; j++) {
        float e = __expf(p[j] - mr);
        sum += e;
        int col = seg * 16 + j;
        Ps[(col >> 3) * 520 + row * 8 + (col & 7)] = f2b(e);
      }
      psum[seg * 64 + row] = sum;
    }
    // rescale O accumulator by alpha (C-layout rows)
    for (int r = 0; r < 4; r++) {
      float a = alpha_s[mrow + r];
      for (int nt = 0; nt < 4; nt++) oacc[nt][r] *= a;
    }
    __syncthreads();
    if (tid < 64)
      rowl[tid] = rowl[tid] * alpha_s[tid] + psum[tid] + psum[64 + tid] + psum[128 + tid] + psum[192 + tid];
    // O += P V
    {
      int r = wv * 16 + l16;
      short8 pa0 = *(const short8*)(Ps + (0 + quad) * 520 + r * 8);
      short8 pa1 = *(const short8*)(Ps + (4 + quad) * 520 + r * 8);
      for (int nt = 0; nt < 4; nt++) {
        short8 vb0 = *(const short8*)(Vt + (0 + quad) * 520 + (nt * 16 + l16) * 8);
        short8 vb1 = *(const short8*)(Vt + (4 + quad) * 520 + (nt * 16 + l16) * 8);
        oacc[nt] = __builtin_amdgcn_mfma_f32_16x16x32_bf16(pa0, vb0, oacc[nt], 0, 0, 0);
        oacc[nt] = __builtin_amdgcn_mfma_f32_16x16x32_bf16(pa1, vb1, oacc[nt], 0, 0, 0);
      }
    }
  }
  __syncthreads();
  // normalize + store O as bf16 [b, s, h, dk]  (row-major [4096, 1024])
  int b = bh >> 4, h = bh & 15;
  for (int nt = 0; nt < 4; nt++) {
    int col = nt * 16 + l16;
    for (int r = 0; r < 4; r++) {
      int rq = wv * 16 + quad * 4 + r;
      float val = oacc[nt][r] / rowl[rq];
      size_t off = ((size_t)(b * S + q0 + rq) * 16 + h) * 64 + col;
      O[off] = f2b(val);
    }
  }
}

extern "C" void kernel_launch(void* const* d_in, const int* in_sizes, int n_in,
                              void* d_out, int out_size, void* d_ws, size_t ws_size,
                              hipStream_t stream) {
  const float* x  = (const float*)d_in[0];
  const int*   tp = (const int*)d_in[1];
  const float* wq = (const float*)d_in[2];
  const float* wk = (const float*)d_in[3];
  const float* wvp = (const float*)d_in[4];
  const float* wo = (const float*)d_in[5];
  float* out = (float*)d_out;

  const int B = 2, S = 2048, D = 1024, H = 16;
  const int BS = B * S;  // 4096

  char* ws = (char*)d_ws;
  u16*   xb    = (u16*)(ws);                                   // 8 MB
  u16*   wqkvb = (u16*)(ws + ((size_t)8 << 20));               // 6 MB
  u16*   wob   = (u16*)(ws + ((size_t)14 << 20));              // 2 MB
  float* ct    = (float*)(ws + ((size_t)16 << 20));            // 256 KB
  float* st    = (float*)(ws + ((size_t)16 << 20) + (256 << 10));
  u16*   cqkv  = (u16*)(ws + ((size_t)17 << 20));              // 24 MB
  u16*   qr    = (u16*)(ws + ((size_t)41 << 20));              // 8 MB
  u16*   kr    = (u16*)(ws + ((size_t)49 << 20));              // 8 MB
  u16*   vr    = (u16*)(ws + ((size_t)57 << 20));              // 8 MB
  u16*   ob    = (u16*)(ws + ((size_t)65 << 20));              // 8 MB -> total 73 MB

  f32_to_bf16_k<<<(BS * D) / 1024, 256, 0, stream>>>(x, xb, BS * D);
  f32_to_bf16_k<<<(D * D) / 1024, 256, 0, stream>>>(wq, wqkvb, D * D);
  f32_to_bf16_k<<<(D * D) / 1024, 256, 0, stream>>>(wk, wqkvb + D * D, D * D);
  f32_to_bf16_k<<<(D * D) / 1024, 256, 0, stream>>>(wvp, wqkvb + 2 * D * D, D * D);
  f32_to_bf16_k<<<(D * D) / 1024, 256, 0, stream>>>(wo, wob, D * D);
  sincos_k<<<(S * 32) / 256, 256, 0, stream>>>(tp, ct, st);

  dim3 g1(3 * D / 128, BS / 128);
  gemm_bt<true><<<g1, 256, 0, stream>>>(xb, wqkvb, cqkv, BS, 3 * D, D);

  repack_k<<<(B * S * H * 32) / 256, 256, 0, stream>>>(cqkv, ct, st, qr, kr, vr);

  dim3 ga(S / 64, B * H);
  attn_k<<<ga, 256, 0, stream>>>(qr, kr, vr, ob, S);

  dim3 g2(D / 128, BS / 128);
  gemm_bt<false><<<g2, 256, 0, stream>>>(ob, wob, out, BS, D, D);
}

// Round 2
// 264.798 us; speedup vs baseline: 1.3546x; 1.3546x over previous
//
#include <hip/hip_runtime.h>

typedef unsigned short u16;
typedef __attribute__((ext_vector_type(8))) short short8;
typedef __attribute__((ext_vector_type(4))) float f32x4;

__device__ __forceinline__ u16 f2b(float f) {
  union { float f; unsigned u; } v; v.f = f;
  unsigned u = v.u;
  return (u16)((u + 0x7FFFu + ((u >> 16) & 1u)) >> 16);
}
__device__ __forceinline__ float b2f(u16 h) {
  union { unsigned u; float f; } v; v.u = ((unsigned)h) << 16; return v.f;
}

// ---------------- fp32 -> bf16 convert (4 elems/thread) ----------------
__global__ __launch_bounds__(256) void f32_to_bf16_k(const float* __restrict__ src,
                                                     u16* __restrict__ dst, int n) {
  int i4 = (blockIdx.x * 256 + threadIdx.x) * 4;
  if (i4 >= n) return;
  const float4 v = *(const float4*)(src + i4);
  uint2 o;
  o.x = (unsigned)f2b(v.x) | ((unsigned)f2b(v.y) << 16);
  o.y = (unsigned)f2b(v.z) | ((unsigned)f2b(v.w) << 16);
  *(uint2*)(dst + i4) = o;
}

// ---------------- sin/cos table: [S][32] ----------------
__global__ __launch_bounds__(256) void sincos_k(const int* __restrict__ pos,
                                                float* __restrict__ ct,
                                                float* __restrict__ st) {
  int idx = blockIdx.x * 256 + threadIdx.x;  // S*32
  int i = idx & 31, s = idx >> 5;
  float p = (float)pos[s];
  float inv = expf(-(float)i * (logf(10000.0f) / 32.0f));
  float ang = p * inv;
  ct[idx] = cosf(ang);
  st[idx] = sinf(ang);
}

// ---------------- bf16 GEMM: C[M,N] = A[M,K] @ B[N,K]^T ----------------
template <bool BF16OUT>
__global__ __launch_bounds__(256) void gemm_bt(const u16* __restrict__ A,
                                               const u16* __restrict__ B,
                                               void* __restrict__ Cv,
                                               int M, int N, int K) {
  __shared__ u16 As[4 * 1032];
  __shared__ u16 Bs[4 * 1032];
  const int tid = threadIdx.x;
  const int wv = tid >> 6, lane = tid & 63;
  const int quad = lane >> 4, l16 = lane & 15;
  const int wm = wv & 1, wn = wv >> 1;
  const int m0 = blockIdx.y * 128, n0 = blockIdx.x * 128;

  f32x4 acc[4][4];
  for (int i = 0; i < 4; i++)
    for (int j = 0; j < 4; j++) acc[i][j] = (f32x4){0.f, 0.f, 0.f, 0.f};

  for (int kt = 0; kt < K; kt += 32) {
    __syncthreads();
    {
      int c = tid;
      int row = c >> 2, k8 = c & 3;
      uint4 a = *(const uint4*)(A + (size_t)(m0 + row) * K + kt + k8 * 8);
      uint4 b = *(const uint4*)(B + (size_t)(n0 + row) * K + kt + k8 * 8);
      *(uint4*)(As + k8 * 1032 + row * 8) = a;
      *(uint4*)(Bs + k8 * 1032 + row * 8) = b;
      c = tid + 256;
      row = c >> 2; k8 = c & 3;
      uint4 a2 = *(const uint4*)(A + (size_t)(m0 + row) * K + kt + k8 * 8);
      uint4 b2 = *(const uint4*)(B + (size_t)(n0 + row) * K + kt + k8 * 8);
      *(uint4*)(As + k8 * 1032 + row * 8) = a2;
      *(uint4*)(Bs + k8 * 1032 + row * 8) = b2;
    }
    __syncthreads();
    short8 af[4], bfr[4];
    for (int i = 0; i < 4; i++)
      af[i] = *(const short8*)(As + quad * 1032 + (wm * 64 + i * 16 + l16) * 8);
    for (int j = 0; j < 4; j++)
      bfr[j] = *(const short8*)(Bs + quad * 1032 + (wn * 64 + j * 16 + l16) * 8);
    for (int i = 0; i < 4; i++)
      for (int j = 0; j < 4; j++)
        acc[i][j] = __builtin_amdgcn_mfma_f32_16x16x32_bf16(af[i], bfr[j], acc[i][j], 0, 0, 0);
  }
  for (int i = 0; i < 4; i++)
    for (int j = 0; j < 4; j++) {
      int col = n0 + wn * 64 + j * 16 + l16;
      for (int r = 0; r < 4; r++) {
        int row = m0 + wm * 64 + i * 16 + quad * 4 + r;
        if (BF16OUT)
          ((u16*)Cv)[(size_t)row * N + col] = f2b(acc[i][j][r]);
        else
          ((float*)Cv)[(size_t)row * N + col] = acc[i][j][r];
      }
    }
}

// ---------------- RoPE + repack: Cqkv bf16 [4096,3072] -> Qr/Kr/Vr [B,H,S,64] bf16 --------
__global__ __launch_bounds__(256) void repack_k(const u16* __restrict__ Cqkv,
                                                const float* __restrict__ ct,
                                                const float* __restrict__ st,
                                                u16* __restrict__ Qr,
                                                u16* __restrict__ Kr,
                                                u16* __restrict__ Vr) {
  int idx = blockIdx.x * 256 + threadIdx.x;  // B*S*H*32 = 2M
  int i = idx & 31;
  int h = (idx >> 5) & 15;
  int s = (idx >> 9) & 2047;
  int b = idx >> 20;
  size_t rowoff = (size_t)(b * 2048 + s) * 3072;
  int colq = h * 64 + 2 * i;
  unsigned qp = *(const unsigned*)(Cqkv + rowoff + colq);
  unsigned kp = *(const unsigned*)(Cqkv + rowoff + 1024 + colq);
  unsigned vp = *(const unsigned*)(Cqkv + rowoff + 2048 + colq);
  float qe = b2f((u16)qp), qo = b2f((u16)(qp >> 16));
  float ke = b2f((u16)kp), ko = b2f((u16)(kp >> 16));
  float c = ct[s * 32 + i], sn = st[s * 32 + i];
  float q0 = c * qe - sn * qo, q1 = sn * qe + c * qo;
  float k0 = c * ke - sn * ko, k1 = sn * ke + c * ko;
  size_t o = ((size_t)(b * 16 + h) * 2048 + s) * 64 + 2 * i;
  *(unsigned*)(Qr + o) = (unsigned)f2b(q0) | ((unsigned)f2b(q1) << 16);
  *(unsigned*)(Kr + o) = (unsigned)f2b(k0) | ((unsigned)f2b(k1) << 16);
  *(unsigned*)(Vr + o) = vp;
}

// ---------------- flash attention v2 ----------------
// Block = 256 thr (4 waves). Each block processes TWO 64-row q-tiles (qt and
// 31-qt) for causal load balance. Per-wave register softmax via shfl_xor over
// the 16 l16 lanes (each wave owns 16 q-rows). Swizzled LDS planes kill the
// round-1 16-way u16 write conflicts. 2 barriers per K-tile.
__global__ __launch_bounds__(256) void attn_k(const u16* __restrict__ Q,
                                              const u16* __restrict__ K,
                                              const u16* __restrict__ V,
                                              u16* __restrict__ O, int S) {
  __shared__ u16 Qs[8 * 520], Ks[8 * 520], Vt[8 * 520], Ps[8 * 520];
  const int tid = threadIdx.x;
  const int wv = tid >> 6, lane = tid & 63, quad = lane >> 4, l16 = lane & 15;
  const int bh = blockIdx.y;
  const int b = bh >> 4, h = bh & 15;
  const u16* Qg = Q + (size_t)bh * S * 64;
  const u16* Kg = K + (size_t)bh * S * 64;
  const u16* Vg = V + (size_t)bh * S * 64;
  const int nqt = S >> 6;  // 32
  const float scale = 0.125f;  // 1/sqrt(64)
  const int rowbase = wv * 16 + quad * 4;  // this lane's first q-row (local)

  for (int t = 0; t < 2; t++) {
    const int qt = t ? (nqt - 1 - (int)blockIdx.x) : (int)blockIdx.x;
    const int q0 = qt * 64;

    for (int c = tid; c < 512; c += 256) {
      int row = c >> 3, k8 = c & 7;
      *(uint4*)(Qs + k8 * 520 + row * 8) =
          *(const uint4*)(Qg + (size_t)(q0 + row) * 64 + k8 * 8);
    }
    __syncthreads();
    short8 qa0, qa1;
    {
      int r = wv * 16 + l16;
      qa0 = *(const short8*)(Qs + quad * 520 + r * 8);
      qa1 = *(const short8*)(Qs + (4 + quad) * 520 + r * 8);
    }
    f32x4 oacc[4];
    for (int j = 0; j < 4; j++) oacc[j] = (f32x4){0.f, 0.f, 0.f, 0.f};
    float m_r[4], l_r[4];
    for (int r = 0; r < 4; r++) { m_r[r] = -1e30f; l_r[r] = 0.f; }

    for (int kt = 0; kt <= qt; ++kt) {
      const int k0 = kt * 64;
      // stage K (plane-major, unswizzled: b128 writes, 8-per-start uniform)
      for (int c = tid; c < 512; c += 256) {
        int row = c >> 3, k8 = c & 7;
        *(uint4*)(Ks + k8 * 520 + row * 8) =
            *(const uint4*)(Kg + (size_t)(k0 + row) * 64 + k8 * 8);
      }
      // stage V transposed, swizzled plane = kp ^ d8 -> 2-way u16 writes (free)
      for (int c = tid; c < 512; c += 256) {
        int sl = c >> 3, d8 = c & 7;
        int kp = sl >> 3, ko = sl & 7;
        u16 tmp[8];
        *(uint4*)tmp = *(const uint4*)(Vg + (size_t)(k0 + sl) * 64 + d8 * 8);
        int pl = kp ^ d8;
#pragma unroll
        for (int i = 0; i < 8; i++) Vt[pl * 520 + (d8 * 8 + i) * 8 + ko] = tmp[i];
      }
      __syncthreads();

      // S = Q K^T (this wave's 16 rows x 64 cols), C-layout
      f32x4 sc[4];
#pragma unroll
      for (int nt = 0; nt < 4; nt++) {
        f32x4 s4 = (f32x4){0.f, 0.f, 0.f, 0.f};
        short8 b0 = *(const short8*)(Ks + quad * 520 + (nt * 16 + l16) * 8);
        short8 b1 = *(const short8*)(Ks + (4 + quad) * 520 + (nt * 16 + l16) * 8);
        s4 = __builtin_amdgcn_mfma_f32_16x16x32_bf16(qa0, b0, s4, 0, 0, 0);
        s4 = __builtin_amdgcn_mfma_f32_16x16x32_bf16(qa1, b1, s4, 0, 0, 0);
        sc[nt] = s4;
      }
      // scale + causal mask + row max (in-register)
      const bool diag = (kt == qt);
      float vmax[4];
#pragma unroll
      for (int r = 0; r < 4; r++) vmax[r] = -3e38f;
#pragma unroll
      for (int nt = 0; nt < 4; nt++) {
        int col = nt * 16 + l16;
#pragma unroll
        for (int r = 0; r < 4; r++) {
          float v = sc[nt][r] * scale;
          if (diag && col > rowbase + r) v = -1e30f;
          sc[nt][r] = v;
          vmax[r] = fmaxf(vmax[r], v);
        }
      }
#pragma unroll
      for (int r = 0; r < 4; r++) {
        vmax[r] = fmaxf(vmax[r], __shfl_xor(vmax[r], 1));
        vmax[r] = fmaxf(vmax[r], __shfl_xor(vmax[r], 2));
        vmax[r] = fmaxf(vmax[r], __shfl_xor(vmax[r], 4));
        vmax[r] = fmaxf(vmax[r], __shfl_xor(vmax[r], 8));
      }
      float al[4], rsum[4];
#pragma unroll
      for (int r = 0; r < 4; r++) {
        float mn = fmaxf(m_r[r], vmax[r]);
        al[r] = __expf(m_r[r] - mn);
        m_r[r] = mn;
        rsum[r] = 0.f;
      }
      // exp -> Ps (bf16, swizzled plane = (cp + 2*(row>>3)) & 7)
#pragma unroll
      for (int nt = 0; nt < 4; nt++) {
        int col = nt * 16 + l16;
        int cp = col >> 3, co = col & 7;
#pragma unroll
        for (int r = 0; r < 4; r++) {
          int row = rowbase + r;
          float p = __expf(sc[nt][r] - m_r[r]);
          rsum[r] += p;
          int A = (cp + 2 * (row >> 3)) & 7;
          Ps[A * 520 + row * 8 + co] = f2b(p);
        }
      }
#pragma unroll
      for (int r = 0; r < 4; r++) {
        rsum[r] += __shfl_xor(rsum[r], 1);
        rsum[r] += __shfl_xor(rsum[r], 2);
        rsum[r] += __shfl_xor(rsum[r], 4);
        rsum[r] += __shfl_xor(rsum[r], 8);
        l_r[r] = l_r[r] * al[r] + rsum[r];
      }
#pragma unroll
      for (int nt = 0; nt < 4; nt++)
#pragma unroll
        for (int r = 0; r < 4; r++) oacc[nt][r] *= al[r];
      // O += P V   (Ps rows are wave-private: no barrier needed)
      {
        int mr = wv * 16 + l16;
        int A0 = (quad + 2 * (mr >> 3)) & 7;
        short8 pa0 = *(const short8*)(Ps + A0 * 520 + mr * 8);
        short8 pa1 = *(const short8*)(Ps + ((A0 + 4) & 7) * 520 + mr * 8);
#pragma unroll
        for (int nt = 0; nt < 4; nt++) {
          int d = nt * 16 + l16, dh = d >> 3;
          int p0 = quad ^ dh;
          short8 vb0 = *(const short8*)(Vt + p0 * 520 + d * 8);
          short8 vb1 = *(const short8*)(Vt + (p0 ^ 4) * 520 + d * 8);
          oacc[nt] = __builtin_amdgcn_mfma_f32_16x16x32_bf16(pa0, vb0, oacc[nt], 0, 0, 0);
          oacc[nt] = __builtin_amdgcn_mfma_f32_16x16x32_bf16(pa1, vb1, oacc[nt], 0, 0, 0);
        }
      }
      __syncthreads();
    }
    // normalize + store O as bf16 [b, s, h, dk]
#pragma unroll
    for (int nt = 0; nt < 4; nt++) {
      int col = nt * 16 + l16;
#pragma unroll
      for (int r = 0; r < 4; r++) {
        int rq = rowbase + r;
        float val = oacc[nt][r] / l_r[r];
        size_t off = ((size_t)(b * S + q0 + rq) * 16 + h) * 64 + col;
        O[off] = f2b(val);
      }
    }
  }
}

extern "C" void kernel_launch(void* const* d_in, const int* in_sizes, int n_in,
                              void* d_out, int out_size, void* d_ws, size_t ws_size,
                              hipStream_t stream) {
  const float* x  = (const float*)d_in[0];
  const int*   tp = (const int*)d_in[1];
  const float* wq = (const float*)d_in[2];
  const float* wk = (const float*)d_in[3];
  const float* wvp = (const float*)d_in[4];
  const float* wo = (const float*)d_in[5];
  float* out = (float*)d_out;

  const int B = 2, S = 2048, D = 1024, H = 16;
  const int BS = B * S;  // 4096

  char* ws = (char*)d_ws;
  u16*   xb    = (u16*)(ws);                                   // 8 MB
  u16*   wqkvb = (u16*)(ws + ((size_t)8 << 20));               // 6 MB
  u16*   wob   = (u16*)(ws + ((size_t)14 << 20));              // 2 MB
  float* ct    = (float*)(ws + ((size_t)16 << 20));            // 256 KB
  float* st    = (float*)(ws + ((size_t)16 << 20) + (256 << 10));
  u16*   cqkv  = (u16*)(ws + ((size_t)17 << 20));              // 24 MB
  u16*   qr    = (u16*)(ws + ((size_t)41 << 20));              // 8 MB
  u16*   kr    = (u16*)(ws + ((size_t)49 << 20));              // 8 MB
  u16*   vr    = (u16*)(ws + ((size_t)57 << 20));              // 8 MB
  u16*   ob    = (u16*)(ws + ((size_t)65 << 20));              // 8 MB

  f32_to_bf16_k<<<(BS * D) / 1024, 256, 0, stream>>>(x, xb, BS * D);
  f32_to_bf16_k<<<(D * D) / 1024, 256, 0, stream>>>(wq, wqkvb, D * D);
  f32_to_bf16_k<<<(D * D) / 1024, 256, 0, stream>>>(wk, wqkvb + D * D, D * D);
  f32_to_bf16_k<<<(D * D) / 1024, 256, 0, stream>>>(wvp, wqkvb + 2 * D * D, D * D);
  f32_to_bf16_k<<<(D * D) / 1024, 256, 0, stream>>>(wo, wob, D * D);
  sincos_k<<<(S * 32) / 256, 256, 0, stream>>>(tp, ct, st);

  dim3 g1(3 * D / 128, BS / 128);
  gemm_bt<true><<<g1, 256, 0, stream>>>(xb, wqkvb, cqkv, BS, 3 * D, D);

  repack_k<<<(B * S * H * 32) / 256, 256, 0, stream>>>(cqkv, ct, st, qr, kr, vr);

  dim3 ga(S / 128, B * H);
  attn_k<<<ga, 256, 0, stream>>>(qr, kr, vr, ob, S);

  dim3 g2(D / 128, BS / 128);
  gemm_bt<false><<<g2, 256, 0, stream>>>(ob, wob, out, BS, D, D);
}

// Round 3
// 222.923 us; speedup vs baseline: 1.6090x; 1.1878x over previous
//
#include <hip/hip_runtime.h>

typedef unsigned short u16;
typedef __attribute__((ext_vector_type(8))) short short8;
typedef __attribute__((ext_vector_type(4))) float f32x4;

__device__ __forceinline__ u16 f2b(float f) {
  union { float f; unsigned u; } v; v.f = f;
  unsigned u = v.u;
  return (u16)((u + 0x7FFFu + ((u >> 16) & 1u)) >> 16);
}
__device__ __forceinline__ u16 f2b_trunc(float f) {
  union { float f; unsigned u; } v; v.f = f;
  return (u16)(v.u >> 16);
}
__device__ __forceinline__ float b2f(u16 h) {
  union { unsigned u; float f; } v; v.u = ((unsigned)h) << 16; return v.f;
}
// async global->LDS, 16B per lane; l must be wave-uniform (lane scatters +lane*16B)
__device__ __forceinline__ void glds16(const u16* g, u16* l) {
  __builtin_amdgcn_global_load_lds((const __attribute__((address_space(1))) void*)g,
                                   (__attribute__((address_space(3))) void*)l, 16, 0, 0);
}

__global__ __launch_bounds__(256) void f32_to_bf16_k(const float* __restrict__ src,
                                                     u16* __restrict__ dst, int n) {
  int i4 = (blockIdx.x * 256 + threadIdx.x) * 4;
  if (i4 >= n) return;
  const float4 v = *(const float4*)(src + i4);
  uint2 o;
  o.x = (unsigned)f2b(v.x) | ((unsigned)f2b(v.y) << 16);
  o.y = (unsigned)f2b(v.z) | ((unsigned)f2b(v.w) << 16);
  *(uint2*)(dst + i4) = o;
}

__global__ __launch_bounds__(256) void sincos_k(const int* __restrict__ pos,
                                                float* __restrict__ ct,
                                                float* __restrict__ st) {
  int idx = blockIdx.x * 256 + threadIdx.x;  // S*32
  int i = idx & 31, s = idx >> 5;
  float p = (float)pos[s];
  float inv = expf(-(float)i * (logf(10000.0f) / 32.0f));
  float ang = p * inv;
  ct[idx] = cosf(ang);
  st[idx] = sinf(ang);
}

// bf16 GEMM (m97 structure): C[M,N] = A[M,K] @ B[N,K]^T; LDS row-major [128][32].
template <bool BF16OUT>
__global__ __launch_bounds__(256) void gemm_bt(const u16* __restrict__ A,
                                               const u16* __restrict__ B,
                                               void* __restrict__ Cv,
                                               int M, int N, int K) {
  __shared__ u16 As[128 * 32];
  __shared__ u16 Bs[128 * 32];
  const int tid = threadIdx.x;
  const int wv = tid >> 6, lane = tid & 63;
  const int quad = lane >> 4, l16 = lane & 15;
  const int wm = wv & 1, wn = wv >> 1;
  const int m0 = blockIdx.y * 128, n0 = blockIdx.x * 128;

  f32x4 acc[4][4];
  for (int i = 0; i < 4; i++)
    for (int j = 0; j < 4; j++) acc[i][j] = (f32x4){0.f, 0.f, 0.f, 0.f};

  for (int kt = 0; kt < K; kt += 32) {
    __syncthreads();
#pragma unroll
    for (int pass = 0; pass < 2; pass++) {
      int c = pass * 256 + tid;
      int row = c >> 2, k8 = c & 3;
      glds16(A + (size_t)(m0 + row) * K + kt + k8 * 8, As + (size_t)(c & ~63) * 8);
      glds16(B + (size_t)(n0 + row) * K + kt + k8 * 8, Bs + (size_t)(c & ~63) * 8);
    }
    __syncthreads();
    short8 af[4], bfr[4];
#pragma unroll
    for (int i = 0; i < 4; i++)
      af[i] = *(const short8*)(As + (wm * 64 + i * 16 + l16) * 32 + quad * 8);
#pragma unroll
    for (int j = 0; j < 4; j++)
      bfr[j] = *(const short8*)(Bs + (wn * 64 + j * 16 + l16) * 32 + quad * 8);
#pragma unroll
    for (int i = 0; i < 4; i++)
#pragma unroll
      for (int j = 0; j < 4; j++)
        acc[i][j] = __builtin_amdgcn_mfma_f32_16x16x32_bf16(af[i], bfr[j], acc[i][j], 0, 0, 0);
  }
  for (int i = 0; i < 4; i++)
    for (int j = 0; j < 4; j++) {
      int col = n0 + wn * 64 + j * 16 + l16;
      for (int r = 0; r < 4; r++) {
        int row = m0 + wm * 64 + i * 16 + quad * 4 + r;
        if (BF16OUT)
          ((u16*)Cv)[(size_t)row * N + col] = f2b(acc[i][j][r]);
        else
          ((float*)Cv)[(size_t)row * N + col] = acc[i][j][r];
      }
    }
}

__global__ __launch_bounds__(256) void repack_k(const u16* __restrict__ Cqkv,
                                                const float* __restrict__ ct,
                                                const float* __restrict__ st,
                                                u16* __restrict__ Qr,
                                                u16* __restrict__ Kr,
                                                u16* __restrict__ Vr) {
  int idx = blockIdx.x * 256 + threadIdx.x;  // B*S*H*32 = 2M
  int i = idx & 31;
  int h = (idx >> 5) & 15;
  int s = (idx >> 9) & 2047;
  int b = idx >> 20;
  size_t rowoff = (size_t)(b * 2048 + s) * 3072;
  int colq = h * 64 + 2 * i;
  unsigned qp = *(const unsigned*)(Cqkv + rowoff + colq);
  unsigned kp = *(const unsigned*)(Cqkv + rowoff + 1024 + colq);
  unsigned vp = *(const unsigned*)(Cqkv + rowoff + 2048 + colq);
  float qe = b2f((u16)qp), qo = b2f((u16)(qp >> 16));
  float ke = b2f((u16)kp), ko = b2f((u16)(kp >> 16));
  float c = ct[s * 32 + i], sn = st[s * 32 + i];
  float q0 = c * qe - sn * qo, q1 = sn * qe + c * qo;
  float k0 = c * ke - sn * ko, k1 = sn * ke + c * ko;
  size_t o = ((size_t)(b * 16 + h) * 2048 + s) * 64 + 2 * i;
  *(unsigned*)(Qr + o) = (unsigned)f2b(q0) | ((unsigned)f2b(q1) << 16);
  *(unsigned*)(Kr + o) = (unsigned)f2b(k0) | ((unsigned)f2b(k1) << 16);
  *(unsigned*)(Vr + o) = vp;
}

// flash attention v3: fixed-max softmax, K-parity split, partials added later.
__global__ __launch_bounds__(256) void attn_k(const u16* __restrict__ Q,
                                              const u16* __restrict__ K,
                                              const u16* __restrict__ V,
                                              float* __restrict__ Op,
                                              float* __restrict__ Lp, int S) {
  __shared__ u16 Qs[8 * 512], Ks[8 * 512], Vt[8 * 520], Ps[8 * 520];
  const int tid = threadIdx.x;
  const int wv = tid >> 6, lane = tid & 63, quad = lane >> 4, l16 = lane & 15;
  const int bh = blockIdx.y, par = blockIdx.z;
  const u16* Qg = Q + (size_t)bh * S * 64;
  const u16* Kg = K + (size_t)bh * S * 64;
  const u16* Vg = V + (size_t)bh * S * 64;
  const int nqt = S >> 6;  // 32
  const float scale = 0.125f;
  const int rowbase = wv * 16 + quad * 4;
  float* Opb = Op + ((size_t)par * 32 + bh) * S * 64;
  float* Lpb = Lp + ((size_t)par * 32 + bh) * S;

  for (int t = 0; t < 2; t++) {
    const int qt = t ? (nqt - 1 - (int)blockIdx.x) : (int)blockIdx.x;
    const int q0 = qt * 64;
    for (int p = wv; p < 8; p += 4)
      glds16(Qg + (size_t)(q0 + lane) * 64 + p * 8, Qs + p * 512);
    __syncthreads();
    short8 qa0 = *(const short8*)(Qs + quad * 512 + (wv * 16 + l16) * 8);
    short8 qa1 = *(const short8*)(Qs + (4 + quad) * 512 + (wv * 16 + l16) * 8);

    f32x4 oacc[4];
    for (int j = 0; j < 4; j++) oacc[j] = (f32x4){0.f, 0.f, 0.f, 0.f};
    float l_r[4] = {0.f, 0.f, 0.f, 0.f};

    for (int kt = par; kt <= qt; kt += 2) {
      const int k0 = kt * 64;
      __syncthreads();
      for (int p = wv; p < 8; p += 4)
        glds16(Kg + (size_t)(k0 + lane) * 64 + p * 8, Ks + p * 512);
      for (int c = tid; c < 512; c += 256) {
        int sl = c >> 3, d8 = c & 7;
        int kp = sl >> 3, ko = sl & 7;
        u16 tmp[8];
        *(uint4*)tmp = *(const uint4*)(Vg + (size_t)(k0 + sl) * 64 + d8 * 8);
        int pl = kp ^ d8;
#pragma unroll
        for (int i = 0; i < 8; i++) Vt[pl * 520 + (d8 * 8 + i) * 8 + ko] = tmp[i];
      }
      __syncthreads();

      const bool diag = (kt == qt);
#pragma unroll
      for (int nt = 0; nt < 4; nt++) {
        f32x4 s4 = (f32x4){0.f, 0.f, 0.f, 0.f};
        short8 b0 = *(const short8*)(Ks + quad * 512 + (nt * 16 + l16) * 8);
        short8 b1 = *(const short8*)(Ks + (4 + quad) * 512 + (nt * 16 + l16) * 8);
        s4 = __builtin_amdgcn_mfma_f32_16x16x32_bf16(qa0, b0, s4, 0, 0, 0);
        s4 = __builtin_amdgcn_mfma_f32_16x16x32_bf16(qa1, b1, s4, 0, 0, 0);
        int col = nt * 16 + l16;
        int cp = col >> 3, co = col & 7;
#pragma unroll
        for (int r = 0; r < 4; r++) {
          float v = s4[r] * scale;
          v = fminf(v, 60.f);
          if (diag && col > rowbase + r) v = -1e30f;  // exp -> 0
          float p = __expf(v);
          l_r[r] += p;
          int row = rowbase + r;
          int A = (cp + 2 * (row >> 3)) & 7;
          Ps[A * 520 + row * 8 + co] = f2b_trunc(p);
        }
      }
      {
        int mr = wv * 16 + l16;
        int A0 = (quad + 2 * (mr >> 3)) & 7;
        short8 pa0 = *(const short8*)(Ps + A0 * 520 + mr * 8);
        short8 pa1 = *(const short8*)(Ps + ((A0 + 4) & 7) * 520 + mr * 8);
#pragma unroll
        for (int nt = 0; nt < 4; nt++) {
          int d = nt * 16 + l16, dh = d >> 3;
          int p0 = quad ^ dh;
          short8 vb0 = *(const short8*)(Vt + p0 * 520 + d * 8);
          short8 vb1 = *(const short8*)(Vt + (p0 ^ 4) * 520 + d * 8);
          oacc[nt] = __builtin_amdgcn_mfma_f32_16x16x32_bf16(pa0, vb0, oacc[nt], 0, 0, 0);
          oacc[nt] = __builtin_amdgcn_mfma_f32_16x16x32_bf16(pa1, vb1, oacc[nt], 0, 0, 0);
        }
      }
    }
#pragma unroll
    for (int r = 0; r < 4; r++) {
      l_r[r] += __shfl_xor(l_r[r], 1);
      l_r[r] += __shfl_xor(l_r[r], 2);
      l_r[r] += __shfl_xor(l_r[r], 4);
      l_r[r] += __shfl_xor(l_r[r], 8);
    }
    if (l16 == 0)
#pragma unroll
      for (int r = 0; r < 4; r++) Lpb[q0 + rowbase + r] = l_r[r];
#pragma unroll
    for (int nt = 0; nt < 4; nt++) {
      int col = nt * 16 + l16;
#pragma unroll
      for (int r = 0; r < 4; r++)
        Opb[(size_t)(q0 + rowbase + r) * 64 + col] = oacc[nt][r];
    }
    __syncthreads();
  }
}

__global__ __launch_bounds__(256) void combine_k(const float* __restrict__ Op,
                                                 const float* __restrict__ Lp,
                                                 u16* __restrict__ O, int S) {
  int idx = blockIdx.x * 256 + threadIdx.x;  // 32*2048*16 = 1M
  int d4 = idx & 15, s = (idx >> 4) & 2047, bh = idx >> 15;
  size_t po = (((size_t)bh * S) + s) * 64 + d4 * 4;
  size_t pstride = (size_t)32 * S * 64;
  float4 a = *(const float4*)(Op + po);
  float4 c = *(const float4*)(Op + pstride + po);
  float l = Lp[(size_t)bh * S + s] + Lp[(size_t)32 * S + (size_t)bh * S + s];
  float rl = 1.f / l;
  int b = bh >> 4, h = bh & 15;
  size_t oo = ((size_t)(b * S + s) * 16 + h) * 64 + d4 * 4;
  uint2 o;
  o.x = (unsigned)f2b((a.x + c.x) * rl) | ((unsigned)f2b((a.y + c.y) * rl) << 16);
  o.y = (unsigned)f2b((a.z + c.z) * rl) | ((unsigned)f2b((a.w + c.w) * rl) << 16);
  *(uint2*)(O + oo) = o;
}

extern "C" void kernel_launch(void* const* d_in, const int* in_sizes, int n_in,
                              void* d_out, int out_size, void* d_ws, size_t ws_size,
                              hipStream_t stream) {
  const float* x  = (const float*)d_in[0];
  const int*   tp = (const int*)d_in[1];
  const float* wq = (const float*)d_in[2];
  const float* wk = (const float*)d_in[3];
  const float* wvp = (const float*)d_in[4];
  const float* wo = (const float*)d_in[5];
  float* out = (float*)d_out;

  const int B = 2, S = 2048, D = 1024, H = 16;
  const int BS = B * S;  // 4096

  // workspace overlay (liveness-checked):
  //  [0,8)    xb      convert -> gemm1
  //  [8,14)   wqkvb   convert -> gemm1
  //  [14,16)  wob     convert -> gemm2
  //  [16,16.5) ct/st  sincos -> repack
  //  [17,41)  cqkv    gemm1 -> repack
  //  [33,33.5) Lpart  attn -> combine (aliases cqkv tail? NO: cqkv live till
  //            repack, Lpart written by attn AFTER repack -> safe)
  //  [41,49)  qr      repack -> attn;  ob aliases it (combine -> gemm2, after attn)
  //  [49,57)  kr, [57,65) vr   repack -> attn
  //  [65,97)  Opart (2x16MB contiguous)  attn -> combine
  char* ws = (char*)d_ws;
  u16*   xb    = (u16*)(ws);
  u16*   wqkvb = (u16*)(ws + ((size_t)8 << 20));
  u16*   wob   = (u16*)(ws + ((size_t)14 << 20));
  float* ct    = (float*)(ws + ((size_t)16 << 20));
  float* st    = (float*)(ws + ((size_t)16 << 20) + (256 << 10));
  u16*   cqkv  = (u16*)(ws + ((size_t)17 << 20));
  float* lpart = (float*)(ws + ((size_t)33 << 20));
  u16*   qr    = (u16*)(ws + ((size_t)41 << 20));
  u16*   ob    = (u16*)(ws + ((size_t)41 << 20));
  u16*   kr    = (u16*)(ws + ((size_t)49 << 20));
  u16*   vr    = (u16*)(ws + ((size_t)57 << 20));
  float* opart = (float*)(ws + ((size_t)65 << 20));

  f32_to_bf16_k<<<(BS * D) / 1024, 256, 0, stream>>>(x, xb, BS * D);
  f32_to_bf16_k<<<(D * D) / 1024, 256, 0, stream>>>(wq, wqkvb, D * D);
  f32_to_bf16_k<<<(D * D) / 1024, 256, 0, stream>>>(wk, wqkvb + D * D, D * D);
  f32_to_bf16_k<<<(D * D) / 1024, 256, 0, stream>>>(wvp, wqkvb + 2 * D * D, D * D);
  f32_to_bf16_k<<<(D * D) / 1024, 256, 0, stream>>>(wo, wob, D * D);
  sincos_k<<<(S * 32) / 256, 256, 0, stream>>>(tp, ct, st);

  dim3 g1(3 * D / 128, BS / 128);
  gemm_bt<true><<<g1, 256, 0, stream>>>(xb, wqkvb, cqkv, BS, 3 * D, D);

  repack_k<<<(B * S * H * 32) / 256, 256, 0, stream>>>(cqkv, ct, st, qr, kr, vr);

  dim3 ga(S / 128, B * H, 2);
  attn_k<<<ga, 256, 0, stream>>>(qr, kr, vr, opart, lpart, S);

  combine_k<<<(32 * S * 16) / 256, 256, 0, stream>>>(opart, lpart, ob, S);

  dim3 g2(D / 128, BS / 128);
  gemm_bt<false><<<g2, 256, 0, stream>>>(ob, wob, out, BS, D, D);
}

// Round 4
// 216.214 us; speedup vs baseline: 1.6589x; 1.0310x over previous
//
#include <hip/hip_runtime.h>

typedef unsigned short u16;
typedef __attribute__((ext_vector_type(8))) short short8;
typedef __attribute__((ext_vector_type(4))) float f32x4;

__device__ __forceinline__ u16 f2b(float f) {
  union { float f; unsigned u; } v; v.f = f;
  unsigned u = v.u;
  return (u16)((u + 0x7FFFu + ((u >> 16) & 1u)) >> 16);
}
__device__ __forceinline__ u16 f2b_trunc(float f) {
  union { float f; unsigned u; } v; v.f = f;
  return (u16)(v.u >> 16);
}
// async global->LDS, 16B per lane; LDS base must be wave-uniform (lane scatters +lane*16B)
__device__ __forceinline__ void glds16(const u16* g, u16* l) {
  __builtin_amdgcn_global_load_lds((const __attribute__((address_space(1))) void*)g,
                                   (__attribute__((address_space(3))) void*)l, 16, 0, 0);
}

// ---------------- fused prep: 5x fp32->bf16 convert + sincos table ----------------
__global__ __launch_bounds__(256) void prep_k(const float* __restrict__ x,
                                              const float* __restrict__ wq,
                                              const float* __restrict__ wk,
                                              const float* __restrict__ wv,
                                              const float* __restrict__ wo,
                                              const int* __restrict__ pos,
                                              u16* __restrict__ xb,
                                              u16* __restrict__ wqkvb,
                                              u16* __restrict__ wob,
                                              float* __restrict__ ct,
                                              float* __restrict__ st) {
  int bx = blockIdx.x, tid = threadIdx.x;
  if (bx < 8192) {
    const float* src; u16* dst; int base;
    if (bx < 4096)      { src = x;  dst = xb;                base = bx; }
    else if (bx < 5120) { src = wq; dst = wqkvb;             base = bx - 4096; }
    else if (bx < 6144) { src = wk; dst = wqkvb + (1 << 20); base = bx - 5120; }
    else if (bx < 7168) { src = wv; dst = wqkvb + (2 << 20); base = bx - 6144; }
    else                { src = wo; dst = wob;               base = bx - 7168; }
    int i4 = base * 1024 + tid * 4;
    const float4 v = *(const float4*)(src + i4);
    uint2 o;
    o.x = (unsigned)f2b(v.x) | ((unsigned)f2b(v.y) << 16);
    o.y = (unsigned)f2b(v.z) | ((unsigned)f2b(v.w) << 16);
    *(uint2*)(dst + i4) = o;
  } else {
    int idx = (bx - 8192) * 256 + tid;  // S*32 = 65536
    int i = idx & 31, s = idx >> 5;
    float p = (float)pos[s];
    float inv = expf(-(float)i * (logf(10000.0f) / 32.0f));
    float ang = p * inv;
    ct[idx] = cosf(ang);
    st[idx] = sinf(ang);
  }
}

// ---------------- gemm1 fused: C = xb @ wqkv^T, epilogue RoPE + head-major scatter ----
// N-tile (128 cols) lies entirely in one of {Q,K,V} (boundaries % 128 == 0).
// Q/K: RoPE via shfl_xor(1) (even/odd cols in adjacent lanes), write [B,H,S,64] bf16.
// V: write transposed [B,H,64,S] bf16.
__global__ __launch_bounds__(256) void gemm_qkv(const u16* __restrict__ A,
                                                const u16* __restrict__ B,
                                                const float* __restrict__ ct,
                                                const float* __restrict__ st,
                                                u16* __restrict__ Qr,
                                                u16* __restrict__ Kr,
                                                u16* __restrict__ VTg) {
  const int M = 4096, N = 3072, K = 1024;
  (void)M; (void)N;
  __shared__ u16 As[128 * 32];
  __shared__ u16 Bs[128 * 32];
  const int tid = threadIdx.x;
  const int wv = tid >> 6, lane = tid & 63;
  const int quad = lane >> 4, l16 = lane & 15;
  const int wm = wv & 1, wn = wv >> 1;
  const int m0 = blockIdx.y * 128, n0 = blockIdx.x * 128;

  f32x4 acc[4][4];
  for (int i = 0; i < 4; i++)
    for (int j = 0; j < 4; j++) acc[i][j] = (f32x4){0.f, 0.f, 0.f, 0.f};

  for (int kt = 0; kt < K; kt += 32) {
    __syncthreads();
#pragma unroll
    for (int pass = 0; pass < 2; pass++) {
      int c = pass * 256 + tid;
      int row = c >> 2, k8 = c & 3;
      glds16(A + (size_t)(m0 + row) * K + kt + k8 * 8, As + (size_t)(c & ~63) * 8);
      glds16(B + (size_t)(n0 + row) * K + kt + k8 * 8, Bs + (size_t)(c & ~63) * 8);
    }
    __syncthreads();
    short8 af[4], bfr[4];
#pragma unroll
    for (int i = 0; i < 4; i++)
      af[i] = *(const short8*)(As + (wm * 64 + i * 16 + l16) * 32 + quad * 8);
#pragma unroll
    for (int j = 0; j < 4; j++)
      bfr[j] = *(const short8*)(Bs + (wn * 64 + j * 16 + l16) * 32 + quad * 8);
#pragma unroll
    for (int i = 0; i < 4; i++)
#pragma unroll
      for (int j = 0; j < 4; j++)
        acc[i][j] = __builtin_amdgcn_mfma_f32_16x16x32_bf16(af[i], bfr[j], acc[i][j], 0, 0, 0);
  }

  const int region = n0 >> 10;  // 0=Q 1=K 2=V (uniform per block)
  if (region < 2) {
    u16* dst = region ? Kr : Qr;
    const int par = l16 & 1;
    for (int i = 0; i < 4; i++)
      for (int j = 0; j < 4; j++) {
        int col = n0 + wn * 64 + j * 16 + l16;
        int cq = col & 1023;
        int h = cq >> 6, d = cq & 63, ifr = (d >> 1) & 31;
        for (int r = 0; r < 4; r++) {
          int row = m0 + wm * 64 + i * 16 + quad * 4 + r;
          int b = row >> 11, s = row & 2047;
          float v = acc[i][j][r];
          float vp = __shfl_xor(v, 1);
          float c = ct[s * 32 + ifr], sn = st[s * 32 + ifr];
          float o = par ? (sn * vp + c * v) : (c * v - sn * vp);
          dst[((size_t)(b * 16 + h) * 2048 + s) * 64 + d] = f2b(o);
        }
      }
  } else {
    for (int i = 0; i < 4; i++)
      for (int j = 0; j < 4; j++) {
        int col = n0 + wn * 64 + j * 16 + l16;
        int cq = col & 1023;
        int h = cq >> 6, d = cq & 63;
        for (int r = 0; r < 4; r++) {
          int row = m0 + wm * 64 + i * 16 + quad * 4 + r;
          int b = row >> 11, s = row & 2047;
          VTg[((size_t)(b * 16 + h) * 64 + d) * 2048 + s] = f2b(acc[i][j][r]);
        }
      }
  }
}

// ---------------- plain bf16 GEMM, fp32 out: C[M,N] = A[M,K] @ B[N,K]^T ----------------
__global__ __launch_bounds__(256) void gemm_bt_f32(const u16* __restrict__ A,
                                                   const u16* __restrict__ B,
                                                   float* __restrict__ C,
                                                   int M, int N, int K) {
  __shared__ u16 As[128 * 32];
  __shared__ u16 Bs[128 * 32];
  const int tid = threadIdx.x;
  const int wv = tid >> 6, lane = tid & 63;
  const int quad = lane >> 4, l16 = lane & 15;
  const int wm = wv & 1, wn = wv >> 1;
  const int m0 = blockIdx.y * 128, n0 = blockIdx.x * 128;

  f32x4 acc[4][4];
  for (int i = 0; i < 4; i++)
    for (int j = 0; j < 4; j++) acc[i][j] = (f32x4){0.f, 0.f, 0.f, 0.f};

  for (int kt = 0; kt < K; kt += 32) {
    __syncthreads();
#pragma unroll
    for (int pass = 0; pass < 2; pass++) {
      int c = pass * 256 + tid;
      int row = c >> 2, k8 = c & 3;
      glds16(A + (size_t)(m0 + row) * K + kt + k8 * 8, As + (size_t)(c & ~63) * 8);
      glds16(B + (size_t)(n0 + row) * K + kt + k8 * 8, Bs + (size_t)(c & ~63) * 8);
    }
    __syncthreads();
    short8 af[4], bfr[4];
#pragma unroll
    for (int i = 0; i < 4; i++)
      af[i] = *(const short8*)(As + (wm * 64 + i * 16 + l16) * 32 + quad * 8);
#pragma unroll
    for (int j = 0; j < 4; j++)
      bfr[j] = *(const short8*)(Bs + (wn * 64 + j * 16 + l16) * 32 + quad * 8);
#pragma unroll
    for (int i = 0; i < 4; i++)
#pragma unroll
      for (int j = 0; j < 4; j++)
        acc[i][j] = __builtin_amdgcn_mfma_f32_16x16x32_bf16(af[i], bfr[j], acc[i][j], 0, 0, 0);
  }
  for (int i = 0; i < 4; i++)
    for (int j = 0; j < 4; j++) {
      int col = n0 + wn * 64 + j * 16 + l16;
      for (int r = 0; r < 4; r++) {
        int row = m0 + wm * 64 + i * 16 + quad * 4 + r;
        C[(size_t)row * N + col] = acc[i][j][r];
      }
    }
}

// ---------------- flash attention v4 ----------------
// Fixed-max softmax (exp2, fused scale), K-parity split, V pre-transposed in
// global [B,H,64,S] and staged via glds16 with XOR chunk swizzle in the global
// addresses (slot s holds chunk s^(d&7)) -> coalesced loads, 2-way frag reads.
__global__ __launch_bounds__(256) void attn_k(const u16* __restrict__ Q,
                                              const u16* __restrict__ K,
                                              const u16* __restrict__ VT,
                                              float* __restrict__ Op,
                                              float* __restrict__ Lp, int S) {
  __shared__ u16 Qs[8 * 512], Ks[8 * 512], Vt[64 * 64], Ps[8 * 520];
  const int tid = threadIdx.x;
  const int wv = tid >> 6, lane = tid & 63, quad = lane >> 4, l16 = lane & 15;
  const int bh = blockIdx.y, par = blockIdx.z;
  const u16* Qg = Q + (size_t)bh * S * 64;
  const u16* Kg = K + (size_t)bh * S * 64;
  const u16* Vg = VT + (size_t)bh * S * 64;  // [64][S] per bh
  const int nqt = S >> 6;  // 32
  const float scale2 = 0.125f * 1.44269504f;  // 1/sqrt(64) * log2(e)
  const int rowbase = wv * 16 + quad * 4;
  float* Opb = Op + ((size_t)par * 32 + bh) * S * 64;
  float* Lpb = Lp + ((size_t)par * 32 + bh) * S;

  // per-lane V staging address components (instruction p covers rows p*8..p*8+7)
  const int vrow_off = lane >> 3;               // d = p*8 + (lane>>3)
  const int vchunk = (lane & 7) ^ (lane >> 3);  // XOR swizzle folded into global addr

  for (int t = 0; t < 2; t++) {
    const int qt = t ? (nqt - 1 - (int)blockIdx.x) : (int)blockIdx.x;
    const int q0 = qt * 64;
    for (int p = wv; p < 8; p += 4)
      glds16(Qg + (size_t)(q0 + lane) * 64 + p * 8, Qs + p * 512);
    __syncthreads();
    short8 qa0 = *(const short8*)(Qs + quad * 512 + (wv * 16 + l16) * 8);
    short8 qa1 = *(const short8*)(Qs + (4 + quad) * 512 + (wv * 16 + l16) * 8);

    f32x4 oacc[4];
    for (int j = 0; j < 4; j++) oacc[j] = (f32x4){0.f, 0.f, 0.f, 0.f};
    float l_r[4] = {0.f, 0.f, 0.f, 0.f};

    for (int kt = par; kt <= qt; kt += 2) {
      const int k0 = kt * 64;
      __syncthreads();
      for (int p = wv; p < 8; p += 4) {
        glds16(Kg + (size_t)(k0 + lane) * 64 + p * 8, Ks + p * 512);
        glds16(Vg + (size_t)(p * 8 + vrow_off) * S + k0 + vchunk * 8, Vt + p * 512);
      }
      __syncthreads();

      const bool diag = (kt == qt);
#pragma unroll
      for (int nt = 0; nt < 4; nt++) {
        f32x4 s4 = (f32x4){0.f, 0.f, 0.f, 0.f};
        short8 b0 = *(const short8*)(Ks + quad * 512 + (nt * 16 + l16) * 8);
        short8 b1 = *(const short8*)(Ks + (4 + quad) * 512 + (nt * 16 + l16) * 8);
        s4 = __builtin_amdgcn_mfma_f32_16x16x32_bf16(qa0, b0, s4, 0, 0, 0);
        s4 = __builtin_amdgcn_mfma_f32_16x16x32_bf16(qa1, b1, s4, 0, 0, 0);
        int col = nt * 16 + l16;
        int cp = col >> 3, co = col & 7;
#pragma unroll
        for (int r = 0; r < 4; r++) {
          float v = s4[r] * scale2;
          v = fminf(v, 86.f);
          if (diag && col > rowbase + r) v = -1e30f;  // exp2 -> 0
          float p = exp2f(v);
          l_r[r] += p;
          int row = rowbase + r;
          int A = (cp + 2 * (row >> 3)) & 7;
          Ps[A * 520 + row * 8 + co] = f2b_trunc(p);
        }
      }
      {
        int mr = wv * 16 + l16;
        int A0 = (quad + 2 * (mr >> 3)) & 7;
        short8 pa0 = *(const short8*)(Ps + A0 * 520 + mr * 8);
        short8 pa1 = *(const short8*)(Ps + ((A0 + 4) & 7) * 520 + mr * 8);
        int sl0 = quad ^ (l16 & 7);
#pragma unroll
        for (int nt = 0; nt < 4; nt++) {
          int d = nt * 16 + l16;
          short8 vb0 = *(const short8*)(Vt + d * 64 + sl0 * 8);
          short8 vb1 = *(const short8*)(Vt + d * 64 + (sl0 ^ 4) * 8);
          oacc[nt] = __builtin_amdgcn_mfma_f32_16x16x32_bf16(pa0, vb0, oacc[nt], 0, 0, 0);
          oacc[nt] = __builtin_amdgcn_mfma_f32_16x16x32_bf16(pa1, vb1, oacc[nt], 0, 0, 0);
        }
      }
    }
#pragma unroll
    for (int r = 0; r < 4; r++) {
      l_r[r] += __shfl_xor(l_r[r], 1);
      l_r[r] += __shfl_xor(l_r[r], 2);
      l_r[r] += __shfl_xor(l_r[r], 4);
      l_r[r] += __shfl_xor(l_r[r], 8);
    }
    if (l16 == 0)
#pragma unroll
      for (int r = 0; r < 4; r++) Lpb[q0 + rowbase + r] = l_r[r];
#pragma unroll
    for (int nt = 0; nt < 4; nt++) {
      int col = nt * 16 + l16;
#pragma unroll
      for (int r = 0; r < 4; r++)
        Opb[(size_t)(q0 + rowbase + r) * 64 + col] = oacc[nt][r];
    }
    __syncthreads();
  }
}

// ---------------- combine partials -> [B,S,H*dk] bf16 ----------------
__global__ __launch_bounds__(256) void combine_k(const float* __restrict__ Op,
                                                 const float* __restrict__ Lp,
                                                 u16* __restrict__ O, int S) {
  int idx = blockIdx.x * 256 + threadIdx.x;  // 32*2048*16 = 1M
  int d4 = idx & 15, s = (idx >> 4) & 2047, bh = idx >> 15;
  size_t po = (((size_t)bh * S) + s) * 64 + d4 * 4;
  size_t pstride = (size_t)32 * S * 64;
  float4 a = *(const float4*)(Op + po);
  float4 c = *(const float4*)(Op + pstride + po);
  float l = Lp[(size_t)bh * S + s] + Lp[(size_t)32 * S + (size_t)bh * S + s];
  float rl = 1.f / l;
  int b = bh >> 4, h = bh & 15;
  size_t oo = ((size_t)(b * S + s) * 16 + h) * 64 + d4 * 4;
  uint2 o;
  o.x = (unsigned)f2b((a.x + c.x) * rl) | ((unsigned)f2b((a.y + c.y) * rl) << 16);
  o.y = (unsigned)f2b((a.z + c.z) * rl) | ((unsigned)f2b((a.w + c.w) * rl) << 16);
  *(uint2*)(O + oo) = o;
}

extern "C" void kernel_launch(void* const* d_in, const int* in_sizes, int n_in,
                              void* d_out, int out_size, void* d_ws, size_t ws_size,
                              hipStream_t stream) {
  const float* x  = (const float*)d_in[0];
  const int*   tp = (const int*)d_in[1];
  const float* wq = (const float*)d_in[2];
  const float* wk = (const float*)d_in[3];
  const float* wvp = (const float*)d_in[4];
  const float* wo = (const float*)d_in[5];
  float* out = (float*)d_out;

  const int B = 2, S = 2048, D = 1024;
  const int BS = B * S;  // 4096
  (void)B; (void)D;

  // workspace overlay (MB):
  //  [0,8)    xb      prep -> gemm1
  //  [8,14)   wqkvb   prep -> gemm1
  //  [14,16)  wob     prep -> gemm2
  //  [16,16.5) ct/st  prep -> gemm1
  //  [17,25)  qr, [25,33) kr, [33,41) vtg   gemm1 -> attn
  //  [41,41.5) lpart  attn -> combine
  //  [42,50)  ob      combine -> gemm2
  //  [50,82)  opart (2x16MB contiguous)  attn -> combine
  char* ws = (char*)d_ws;
  u16*   xb    = (u16*)(ws);
  u16*   wqkvb = (u16*)(ws + ((size_t)8 << 20));
  u16*   wob   = (u16*)(ws + ((size_t)14 << 20));
  float* ct    = (float*)(ws + ((size_t)16 << 20));
  float* st    = (float*)(ws + ((size_t)16 << 20) + (256 << 10));
  u16*   qr    = (u16*)(ws + ((size_t)17 << 20));
  u16*   kr    = (u16*)(ws + ((size_t)25 << 20));
  u16*   vtg   = (u16*)(ws + ((size_t)33 << 20));
  float* lpart = (float*)(ws + ((size_t)41 << 20));
  u16*   ob    = (u16*)(ws + ((size_t)42 << 20));
  float* opart = (float*)(ws + ((size_t)50 << 20));

  prep_k<<<8448, 256, 0, stream>>>(x, wq, wk, wvp, wo, tp, xb, wqkvb, wob, ct, st);

  dim3 g1(3 * D / 128, BS / 128);
  gemm_qkv<<<g1, 256, 0, stream>>>(xb, wqkvb, ct, st, qr, kr, vtg);

  dim3 ga(S / 128, 32, 2);
  attn_k<<<ga, 256, 0, stream>>>(qr, kr, vtg, opart, lpart, S);

  combine_k<<<(32 * S * 16) / 256, 256, 0, stream>>>(opart, lpart, ob, S);

  dim3 g2(D / 128, BS / 128);
  gemm_bt_f32<<<g2, 256, 0, stream>>>(ob, wob, out, BS, D, D);
}